// Round 8
// baseline (264.219 us; speedup 1.0000x reference)
//
#include <hip/hip_runtime.h>
#include <math.h>

#define ALPHA 0.2f

// xbf / hamT row stride in shorts (17 lines — kills L1 set-aliasing for k_h)
#define XS   544

typedef __attribute__((ext_vector_type(8))) short short8;
typedef __attribute__((ext_vector_type(4))) float f32x4;
typedef __attribute__((ext_vector_type(4))) int i32x4;

__device__ __forceinline__ unsigned short f2bf(float f) {
    unsigned int x = __float_as_uint(f);
    x += 0x7fffu + ((x >> 16) & 1u);   // RNE
    return (unsigned short)(x >> 16);
}
__device__ __forceinline__ unsigned int pack_rne(float lo, float hi) {
    return (unsigned int)f2bf(lo) | ((unsigned int)f2bf(hi) << 16);
}
// truncating bf16 pack (bias cancels in w/L since L sums the same truncated w)
__device__ __forceinline__ unsigned int pack_trunc(float lo, float hi) {
    return __builtin_amdgcn_perm(__float_as_uint(hi), __float_as_uint(lo), 0x07060302u);
}
// bit j of x -> 0x0 / 0xFFFFFFFF
__device__ __forceinline__ unsigned int bitmask1(unsigned int x, int j) {
    return (unsigned int)(((int)(x << (31 - j))) >> 31);
}

// ---------------------------------------------------------------------------
// K0 (fused prep): [0,1024): x fp32->bf16 (padded rows). [1024,1152):
// hamilton transposed bf16. [1152,3200): adj -> 1-bit mask, 32/thread.
// ---------------------------------------------------------------------------
__global__ __launch_bounds__(256) void k_prep(const float* __restrict__ x,
                                              const float* __restrict__ W,
                                              const int* __restrict__ adj,
                                              unsigned short* __restrict__ xbf,
                                              unsigned short* __restrict__ hamT,
                                              unsigned int* __restrict__ adjp32) {
    const int b = blockIdx.x;
    if (b < 1024) {                       // ---- x convert: 2M elems, 8/thread
        const int gid = b * 256 + threadIdx.x;
        const int row = gid >> 6, c8 = (gid & 63) * 8;
        const float4* xp = (const float4*)x + (size_t)gid * 2;
        const float4 f0 = xp[0], f1 = xp[1];
        const uint4 o = {pack_rne(f0.x, f0.y), pack_rne(f0.z, f0.w),
                         pack_rne(f1.x, f1.y), pack_rne(f1.z, f1.w)};
        *(uint4*)(xbf + (size_t)row * XS + c8) = o;
    } else if (b < 1152) {                // ---- hamilton: sign mask 0x5390
        const int gid = (b - 1024) * 256 + threadIdx.x;    // 32768
        const int head = gid >> 13;
        const int rem  = gid & 8191;
        const int o = rem >> 6, f8 = rem & 63;
        const int ob = o >> 5, oc = o & 31;
        float v[8];
#pragma unroll
        for (int j = 0; j < 8; j++) {
            const int f = f8 * 8 + j;
            const int bq = f >> 7, f0 = f & 127;
            const float s = ((0x5390u >> ((bq << 2) | ob)) & 1u) ? -1.0f : 1.0f;
            v[j] = s * W[(head << 14) + (f0 << 7) + (((bq ^ ob) << 5) | oc)];
        }
        const uint4 pk = {pack_rne(v[0], v[1]), pack_rne(v[2], v[3]),
                          pack_rne(v[4], v[5]), pack_rne(v[6], v[7])};
        *(uint4*)(hamT + (size_t)(head * 128 + o) * XS + f8 * 8) = pk;
    } else {                              // ---- adj bit-pack: 64 MB -> 2 MB
        const int gid = (b - 1152) * 256 + threadIdx.x;    // 0..524287
        const int4* ap = (const int4*)(adj + (size_t)gid * 32);
        unsigned int u = 0;
#pragma unroll
        for (int q = 0; q < 8; q++) {
            const int4 v = ap[q];
            u |= (v.x > 0 ? 1u : 0u) << (q * 4);
            u |= (v.y > 0 ? 2u : 0u) << (q * 4);
            u |= (v.z > 0 ? 4u : 0u) << (q * 4);
            u |= (v.w > 0 ? 8u : 0u) << (q * 4);
        }
        adjp32[gid] = u;
    }
}

// ---------------------------------------------------------------------------
// K1: h = x @ ham via bf16 MFMA. Block: 4 waves x 16 rows, 128 cols.
// Writes hBT in CHUNK-MAJOR layout (R6-proven):
//   hBT[head][c][col][s] shorts; c=m>>5, s=m&31, col=ct*16+nl
//   offset = head*524288 + c*4096 + col*32 + s   (1 MB/head, 4 MB total)
// ---------------------------------------------------------------------------
__global__ __launch_bounds__(256) void k_h(const unsigned short* __restrict__ xbf,
                                           const unsigned short* __restrict__ hamT,
                                           const float* __restrict__ a,
                                           unsigned short* __restrict__ hBT,
                                           float2* __restrict__ fsE,
                                           float2* __restrict__ fdE) {
    const int t = threadIdx.x;
    const int head = blockIdx.y;
    const int n0 = blockIdx.x * 64;
    const int wv = t >> 6, lane = t & 63;
    const int quad = lane >> 4, nl = lane & 15;
    const unsigned short* ap = xbf + (size_t)(n0 + wv * 16 + nl) * XS + quad * 8;
    const unsigned short* bp = hamT + (size_t)(head * 128 + nl) * XS + quad * 8;
    f32x4 acc[8];
#pragma unroll
    for (int ct = 0; ct < 8; ct++) acc[ct] = (f32x4){0.f, 0.f, 0.f, 0.f};
    for (int kc = 0; kc < 16; kc++) {
        const short8 af = *(const short8*)(ap + kc * 32);
#pragma unroll
        for (int ct = 0; ct < 8; ct++) {
            const short8 bf_ = *(const short8*)(bp + (size_t)ct * 16 * XS + kc * 32);
            acc[ct] = __builtin_amdgcn_mfma_f32_16x16x32_bf16(af, bf_, acc[ct], 0, 0, 0);
        }
    }
    const int rbase = n0 + wv * 16 + quad * 4;      // m-index in k_attn's view
    const int c = rbase >> 5, s = rbase & 31;
#pragma unroll
    for (int ct = 0; ct < 8; ct++) {
        const uint2 pk = {pack_rne(acc[ct][0], acc[ct][1]), pack_rne(acc[ct][2], acc[ct][3])};
        *(uint2*)(hBT + (size_t)head * 524288 + (size_t)c * 4096
                  + (ct * 16 + nl) * 32 + s) = pk;
    }
    float fsr[4] = {0.f, 0.f, 0.f, 0.f}, fdr[4] = {0.f, 0.f, 0.f, 0.f};
#pragma unroll
    for (int ct = 0; ct < 8; ct++) {
        const int col = ct * 16 + nl;
        const float as = a[head * 256 + col];
        const float ad = a[head * 256 + 128 + col];
#pragma unroll
        for (int r = 0; r < 4; r++) {
            fsr[r] += acc[ct][r] * as;
            fdr[r] += acc[ct][r] * ad;
        }
    }
#pragma unroll
    for (int off = 1; off < 16; off <<= 1)
#pragma unroll
        for (int r = 0; r < 4; r++) {
            fsr[r] += __shfl_xor(fsr[r], off, 64);
            fdr[r] += __shfl_xor(fdr[r], off, 64);
        }
    if (nl == 0) {
#pragma unroll
        for (int r = 0; r < 4; r++) {
            const int n = rbase + r;
            fsE[(head << 12) + n] = make_float2(__expf(fsr[r]), __expf(ALPHA * fsr[r]));
            fdE[(head << 12) + n] = make_float2(__expf(fdr[r]), __expf(ALPHA * fdr[r]));
        }
    }
}

// ---------------------------------------------------------------------------
// K2: h' = softmax(mask(leaky(fs+fd))) @ h, fused ELU.  LDS-STAGED B.
// Synthesis of R0-R7: the limiter is fixed per-chunk latency exposure on the
// per-wave global B-path (stall ~2-3k cyc/chunk regardless of chunk size;
// immune to TLP (R3), convoy (R6), stealing (R7)). Fix: stage each B-chunk
// ONCE per CU into LDS (reg-staged, T14) and let all 4 waves ds_read it —
// per-CU LSU B-traffic 4x lower than R0, ds_reads are a conflict-free linear
// 1KB sweep. Waves split N (16 rows each, R6-proven rt=1 mapping) and convoy
// the same m; each wave owns its rows end-to-end (no combine, no k_comb).
// Pipeline: 64 phases x 64 m (16 KB), double-buffered; RAW s_barrier +
// lgkmcnt(0) only — NO __syncthreads (its vmcnt(0) would drain the global
// prefetch queue each phase = the documented ~20% barrier-drain stall).
// Correctness: data flows global->VGPR->ds_write (compiler-tracked waits);
// one barrier per phase separates write(buf^1)/read(buf) hazards; memory-
// clobber asm + sched_barrier(0) pin ds ops to their phase (rules #18).
// Launch-bounds 2nd arg banned (R1/R2/R4: 128-VGPR cap -> spill).
// ---------------------------------------------------------------------------
#define WELT(e1, ea, j, bits, es) \
    __uint_as_float(__float_as_uint(fmaxf((es).x * (e1), (es).y * (ea))) & bitmask1((bits), (j)))
#define WPK(f4, jb, bits, es) \
    pack_trunc(WELT((f4).x, (f4).y, (jb), (bits), (es)), \
               WELT((f4).z, (f4).w, (jb) + 1, (bits), (es)))

#define GLOAD(phn) do {                                                    \
    _Pragma("unroll")                                                      \
    for (int _i = 0; _i < 4; _i++)                                         \
        Gst[_i] = gB[(phn) * 1024 + _i * 256 + t];                         \
} while (0)

#define DSWRITE(wrp) do {                                                  \
    _Pragma("unroll")                                                      \
    for (int _i = 0; _i < 4; _i++)                                         \
        *(uint4*)((wrp) + t * 8 + _i * 2048) = Gst[_i];                    \
} while (0)

#define KFLOAD(S, c) do {                                                  \
    const int _c = (c) & 127;                                              \
    Kst[S] = ap[_c * 4];                                                   \
    _Pragma("unroll")                                                      \
    for (int _q = 0; _q < 4; _q++) Fst[S][_q] = fdb[_c * 16 + _q];         \
} while (0)

#define EXECC(S, kk, rdp) do {                                             \
    const i32x4 _ai = {(int)WPK(Fst[S][0], 0, Kst[S], es),                 \
                       (int)WPK(Fst[S][1], 2, Kst[S], es),                 \
                       (int)WPK(Fst[S][2], 4, Kst[S], es),                 \
                       (int)WPK(Fst[S][3], 6, Kst[S], es)};                \
    const short8 _af = __builtin_bit_cast(short8, _ai);                    \
    _Pragma("unroll")                                                      \
    for (int _ct = 0; _ct < 8; _ct++) {                                    \
        const short8 _bf = *(const short8*)((rdp) + (kk) * 4096 + _ct * 512); \
        acc[_ct] = __builtin_amdgcn_mfma_f32_16x16x32_bf16(                \
            _af, _bf, acc[_ct], 0, 0, 0);                                  \
    }                                                                      \
    accL = __builtin_amdgcn_mfma_f32_16x16x32_bf16(_af, ones, accL, 0, 0, 0); \
} while (0)

__global__ __launch_bounds__(256) void k_attn(const unsigned char* __restrict__ adjp,
                                              const float2* __restrict__ fsE,
                                              const float2* __restrict__ fdE,
                                              const unsigned short* __restrict__ hBT,
                                              float* __restrict__ out) {
    __shared__ unsigned short Bs[2][8192];     // 2 x 16 KB phase buffers
    const int t = threadIdx.x;
    const int head = blockIdx.x & 3;           // XCD-pinned head
    const int n0 = (blockIdx.x >> 2) * 64;     // 64-row tiles, 256 blocks
    const int wv = t >> 6, lane = t & 63;
    const int quad = lane >> 4, nl = lane & 15;
    const int row = n0 + wv * 16 + nl;         // this lane's attention row
    const float2 es = fsE[(head << 12) + row];
    const unsigned char* ap = adjp + ((size_t)row << 9) + quad;
    const float4* fdb = (const float4*)(fdE + (head << 12) + quad * 8);
    const uint4* gB = (const uint4*)(hBT + (size_t)head * 524288);
    const short8 ones = __builtin_bit_cast(short8,
        (i32x4){0x3F803F80, 0x3F803F80, 0x3F803F80, 0x3F803F80});
    f32x4 acc[8], accL;
    accL = (f32x4){0.f, 0.f, 0.f, 0.f};
#pragma unroll
    for (int ct = 0; ct < 8; ct++) acc[ct] = (f32x4){0.f, 0.f, 0.f, 0.f};
    uint4 Gst[4];
    unsigned int Kst[2];
    float4 Fst[2][4];

    // ---- prologue: stage phase 0, prefetch phase 1 + first K/F ------------
    GLOAD(0);
    DSWRITE(&Bs[0][0]);
    GLOAD(1);
    KFLOAD(0, 0);
    KFLOAD(1, 1);
    asm volatile("s_waitcnt lgkmcnt(0)" ::: "memory");
    __builtin_amdgcn_s_barrier();
    __builtin_amdgcn_sched_barrier(0);

    for (int ph = 0; ph < 64; ph++) {
        unsigned short* wr = &Bs[(ph + 1) & 1][0];
        const unsigned short* rd = &Bs[ph & 1][nl * 32 + quad * 8];
        if (ph < 63) {
            DSWRITE(wr);                       // phase ph+1 data (vm-wait auto)
            if (ph < 62) GLOAD(ph + 2);        // refill Gst for next phase
        }
        EXECC(0, 0, rd);
        KFLOAD(0, 2 * ph + 2);                 // wrap load harmless
        EXECC(1, 1, rd);
        KFLOAD(1, 2 * ph + 3);
        __builtin_amdgcn_sched_barrier(0);
        asm volatile("s_waitcnt lgkmcnt(0)" ::: "memory");   // ds_writes landed
        __builtin_amdgcn_s_barrier();          // no vmcnt drain: prefetch lives
        __builtin_amdgcn_sched_barrier(0);
    }

    // ---- epilogue: each wave owns its rows completely (R6-proven) ---------
    float iL[4];
#pragma unroll
    for (int r = 0; r < 4; r++) iL[r] = (accL[r] > 0.f) ? (1.0f / accL[r]) : 0.0f;
#pragma unroll
    for (int ct = 0; ct < 8; ct++) {
#pragma unroll
        for (int r = 0; r < 4; r++) {
            float v = acc[ct][r] * iL[r];
            v = v > 0.f ? v : (__expf(v) - 1.0f);   // ELU(alpha=1)
            out[(size_t)(n0 + wv * 16 + quad * 4 + r) * 512
                + head * 128 + ct * 16 + nl] = v;
        }
    }
}

extern "C" void kernel_launch(void* const* d_in, const int* in_sizes, int n_in,
                              void* d_out, int out_size, void* d_ws, size_t ws_size,
                              hipStream_t stream) {
    (void)in_sizes; (void)n_in; (void)out_size; (void)ws_size;
    const float* x   = (const float*)d_in[0];   // (4096,512) fp32
    const int*   adj = (const int*)d_in[1];     // (4096,4096) i32
    const float* W   = (const float*)d_in[2];   // (4,128,128) fp32
    const float* a   = (const float*)d_in[3];   // (4,256) fp32
    float* out = (float*)d_out;                 // (4096,512) fp32

    // ws layout, 11.57 MB (R6-proven):
    char* ws = (char*)d_ws;
    unsigned short* hBT  = (unsigned short*)(ws);             // 4 MB chunk-major
    unsigned char*  adjp = (unsigned char*)(ws + 4194304);    // 2 MB bitmask
    float2*         fsE  = (float2*)(ws + 6291456);           // 128 KB
    float2*         fdE  = (float2*)(ws + 6422528);           // 128 KB
    unsigned short* xbf  = (unsigned short*)(ws + 6553600);   // 4456448 B
    unsigned short* hamT = (unsigned short*)(ws + 11010048);  // 557056 B

    hipLaunchKernelGGL(k_prep, dim3(3200),  dim3(256), 0, stream,
                       x, W, adj, xbf, hamT, (unsigned int*)adjp);
    hipLaunchKernelGGL(k_h,    dim3(64, 4), dim3(256), 0, stream, xbf, hamT, a, hBT, fsE, fdE);
    hipLaunchKernelGGL(k_attn, dim3(256),   dim3(256), 0, stream, adjp, fsE, fdE, hBT, out);
}